// Round 12
// baseline (356.593 us; speedup 1.0000x reference)
//
#include <hip/hip_runtime.h>

#ifndef __has_builtin
#define __has_builtin(x) 0
#endif

#define T_STEPS 512
#define BATCH   128
#define DIN     256
#define HID     256
#define WPLD    (DIN + HID)   // 512

// Volatile asm loads: results are NOT rematerializable (cheap insurance).
#define ASM_LOAD4(dst, ptr) \
    asm volatile("global_load_dwordx4 %0, %1, off" : "=v"(dst) : "v"(ptr))
#define ASM_LOAD1(dst, ptr) \
    asm volatile("global_load_dword %0, %1, off" : "=v"(dst) : "v"(ptr))

// Step barrier WITHOUT vmcnt drain: waits only for LDS ops (hbuf publish),
// lets the per-step global h-store stay in flight across the barrier.
// (No other thread ever reads that store's location -> legal.)
#define STEP_BARRIER() do {                                   \
    asm volatile("s_waitcnt lgkmcnt(0)" ::: "memory");        \
    __builtin_amdgcn_s_barrier();                             \
    __builtin_amdgcn_sched_barrier(0);                        \
} while (0)

// ---------------- cross-lane helpers (all verified in passing runs) ----------------
template<int CTRL>
__device__ __forceinline__ float dppmov(float x) {
    // 0xB1=quad xor1, 0x4E=quad xor2, 0x124=row_ror:4, 0x128=row_ror:8
    return __int_as_float(__builtin_amdgcn_update_dpp(0, __float_as_int(x), CTRL, 0xF, 0xF, true));
}
template<int PAT>
__device__ __forceinline__ float swz(float x) {
    return __int_as_float(__builtin_amdgcn_ds_swizzle(__float_as_int(x), PAT));
}
__device__ __forceinline__ float lane_xor16(float v, int l) {
#if __has_builtin(__builtin_amdgcn_permlane16_swap)
    auto r = __builtin_amdgcn_permlane16_swap(__float_as_uint(v), __float_as_uint(v), false, false);
    return __uint_as_float((l & 16) ? r[0] : r[1]);
#else
    return swz<0x401F>(v);
#endif
}
__device__ __forceinline__ float lane_xor32(float v, int l) {
#if __has_builtin(__builtin_amdgcn_permlane32_swap)
    auto r = __builtin_amdgcn_permlane32_swap(__float_as_uint(v), __float_as_uint(v), false, false);
    return __uint_as_float((l & 32) ? r[0] : r[1]);
#else
    return __shfl_xor(v, 32);
#endif
}
__device__ __forceinline__ float rcp_f(float x) {
#if __has_builtin(__builtin_amdgcn_rcpf)
    return __builtin_amdgcn_rcpf(x);
#else
    return 1.0f / x;
#endif
}

// ---------------------------------------------------------------------------
// Kernel 1: px[b][t][q] = sum_d x[t,b,d]*Wp[q,d] + qp[q]
// ---------------------------------------------------------------------------
__global__ __launch_bounds__(256) void qlstm_projx(const float* __restrict__ x,
                                                   const float* __restrict__ Wp,
                                                   const float* __restrict__ qp,
                                                   float* __restrict__ px) {
    const int wave = threadIdx.x >> 6;
    const int lane = threadIdx.x & 63;
    const int row  = blockIdx.x * 4 + wave;       // row = t*BATCH + b

    const float4 xv = ((const float4*)(x + (size_t)row * DIN))[lane];
    float acc[8];
#pragma unroll
    for (int Q = 0; Q < 8; ++Q) {
        float4 w = ((const float4*)(Wp + Q * WPLD))[lane];
        acc[Q] = xv.x * w.x + xv.y * w.y + xv.z * w.z + xv.w * w.w;
    }
#pragma unroll
    for (int Q = 0; Q < 8; ++Q) {
        acc[Q] += dppmov<0xB1>(acc[Q]);
        acc[Q] += dppmov<0x4E>(acc[Q]);
        acc[Q] += swz<0x101F>(acc[Q]);
    }
    float p = acc[0];
#pragma unroll
    for (int j = 1; j < 8; ++j) p = ((lane & 7) == j) ? acc[j] : p;
    p += swz<0x201F>(p);
    p += swz<0x401F>(p);
    p += __shfl_xor(p, 32);
    if (lane < 8) {
        const int bb = row & (BATCH - 1);
        const int tt = row >> 7;
        px[(size_t)bb * (T_STEPS * 8) + tt * 8 + lane] = p + qp[lane];
    }
}

// ---------------------------------------------------------------------------
// Kernel 2: recurrence. R8 structure, byte-identical per-step math and store
// order (known-passing). ONLY change: the per-step __syncthreads() is replaced
// by lgkmcnt(0) + raw s_barrier, which does NOT drain vmcnt — the global
// h-store's write-ack retires off the critical path.
// ---------------------------------------------------------------------------
__global__ __launch_bounds__(256, 1) void qlstm_seq(const float* __restrict__ hx,
                                                    const float* __restrict__ cx,
                                                    const float* __restrict__ Wp,
                                                    const float* __restrict__ Wg,
                                                    const float* __restrict__ bg,
                                                    const float* __restrict__ px,
                                                    float* __restrict__ out) {
    __shared__ float px_lds[(T_STEPS + 1) * 8];   // +8 pad for prefetch overrun
    __shared__ float hbuf[2][HID];                // double-buffered h

    const int tid = threadIdx.x;
    const int w   = tid >> 6;     // wave id 0..3
    const int l   = tid & 63;     // lane
    const int b   = blockIdx.x;
    const int cg  = (w << 6) | l; // this thread's gate/LSTM column
    const bool lane0 = (l == 0);

    // ---- weight loads (asm: non-rematerializable) ----
    float4 wph[8];                // Wp[q][256+4l .. +3]  (same for all waves)
#pragma unroll
    for (int q = 0; q < 8; ++q) {
        const float* a = Wp + q * WPLD + DIN + 4 * l;
        ASM_LOAD4(wph[q], a);
    }
    float4 WG0[4], WG1[4];        // Wg row (G*256+cg), floats 0..7
#pragma unroll
    for (int G = 0; G < 4; ++G) {
        const float* r = Wg + (size_t)(G * HID + cg) * 8;
        ASM_LOAD4(WG0[G], r);
        ASM_LOAD4(WG1[G], r + 4);
    }
    float bgc[4];                 // bg[G*256+cg]
#pragma unroll
    for (int G = 0; G < 4; ++G) {
        const float* a = bg + G * HID + cg;
        ASM_LOAD1(bgc[G], a);
    }

    // preload all px for this b (4096 floats = 1024 float4, 4 per thread)
    {
        const float4* pg = (const float4*)(px + (size_t)b * (T_STEPS * 8));
        float4* pl = (float4*)px_lds;
#pragma unroll
        for (int j = 0; j < 4; ++j) pl[j * 256 + tid] = pg[j * 256 + tid];
    }

    float c = cx[b * HID + cg];
    hbuf[0][tid] = hx[b * HID + tid];

    asm volatile("s_waitcnt vmcnt(0)" ::: "memory");
    __builtin_amdgcn_sched_barrier(0);
    __syncthreads();   // hbuf[0] + px_lds ready (full barrier once, prologue only)

    // prefetch px for t=0
    float4 pxa = *(const float4*)(&px_lds[0]);
    float4 pxb = *(const float4*)(&px_lds[4]);

    float* outp = out + (size_t)b * HID + cg;

    for (int t = 0; t < T_STEPS; ++t) {
        // full h for proj: lane l reads h[4l..4l+3] (all waves read same data)
        const float4 h4 = *(const float4*)&hbuf[t & 1][4 * l];

        const float pxv[8] = {pxa.x, pxa.y, pxa.z, pxa.w, pxb.x, pxb.y, pxb.z, pxb.w};

        // per-lane partials (px folded into lane 0); full in-wave allreduce
        float s[8];
#pragma unroll
        for (int q = 0; q < 8; ++q) {
            float v = lane0 ? pxv[q] : 0.f;
            v = fmaf(h4.x, wph[q].x, v);
            v = fmaf(h4.y, wph[q].y, v);
            v = fmaf(h4.z, wph[q].z, v);
            v = fmaf(h4.w, wph[q].w, v);
            s[q] = v;
        }
#pragma unroll
        for (int q = 0; q < 8; ++q) {
            float v = s[q];
            v += dppmov<0xB1>(v);        // xor1
            v += dppmov<0x4E>(v);        // xor2
            v += dppmov<0x124>(v);       // ror4
            v += dppmov<0x128>(v);       // ror8
            v += lane_xor16(v, l);
            v += lane_xor32(v, l);
            s[q] = v;
        }

        const float C0 = __cosf(s[0]);
        const float C1 = __cosf(s[1]);
        const float C2 = __cosf(s[2]);
        const float C3 = __cosf(s[3]);
        const float C4 = __cosf(s[4]);
        const float C5 = __cosf(s[5]);
        const float C6 = __cosf(s[6]);
        const float C7 = __cosf(s[7]);

        // prefetch px for t+1 (off critical path)
        pxa = *(const float4*)(&px_lds[(t + 1) * 8]);
        pxb = *(const float4*)(&px_lds[(t + 1) * 8 + 4]);

        // prefix products: qo[0]=C1..C7, qo[k>=1]=C0..Ck
        const float d01 = C0 * C1, d23 = C2 * C3, d45 = C4 * C5, d67 = C6 * C7;
        float qo[8];
        qo[1] = d01;
        qo[2] = d01 * C2;
        qo[3] = d01 * d23;
        qo[4] = qo[3] * C4;
        qo[5] = qo[3] * d45;
        qo[6] = qo[5] * C6;
        qo[7] = qo[5] * d67;
        qo[0] = (C1 * d23) * (d45 * d67);

        // gates for this thread's single column (tree-structured)
        float gf, gi, gg, go;
        {
            float a0, a1;
            a0 = fmaf(WG0[0].x, qo[0], bgc[0]);  a0 = fmaf(WG0[0].y, qo[1], a0);
            a0 = fmaf(WG0[0].z, qo[2], a0);      a0 = fmaf(WG0[0].w, qo[3], a0);
            a1 = WG1[0].x * qo[4];               a1 = fmaf(WG1[0].y, qo[5], a1);
            a1 = fmaf(WG1[0].z, qo[6], a1);      a1 = fmaf(WG1[0].w, qo[7], a1);
            gf = a0 + a1;
            a0 = fmaf(WG0[1].x, qo[0], bgc[1]);  a0 = fmaf(WG0[1].y, qo[1], a0);
            a0 = fmaf(WG0[1].z, qo[2], a0);      a0 = fmaf(WG0[1].w, qo[3], a0);
            a1 = WG1[1].x * qo[4];               a1 = fmaf(WG1[1].y, qo[5], a1);
            a1 = fmaf(WG1[1].z, qo[6], a1);      a1 = fmaf(WG1[1].w, qo[7], a1);
            gi = a0 + a1;
            a0 = fmaf(WG0[2].x, qo[0], bgc[2]);  a0 = fmaf(WG0[2].y, qo[1], a0);
            a0 = fmaf(WG0[2].z, qo[2], a0);      a0 = fmaf(WG0[2].w, qo[3], a0);
            a1 = WG1[2].x * qo[4];               a1 = fmaf(WG1[2].y, qo[5], a1);
            a1 = fmaf(WG1[2].z, qo[6], a1);      a1 = fmaf(WG1[2].w, qo[7], a1);
            gg = a0 + a1;
            a0 = fmaf(WG0[3].x, qo[0], bgc[3]);  a0 = fmaf(WG0[3].y, qo[1], a0);
            a0 = fmaf(WG0[3].z, qo[2], a0);      a0 = fmaf(WG0[3].w, qo[3], a0);
            a1 = WG1[3].x * qo[4];               a1 = fmaf(WG1[3].y, qo[5], a1);
            a1 = fmaf(WG1[3].z, qo[6], a1);      a1 = fmaf(WG1[3].w, qo[7], a1);
            go = a0 + a1;
        }

        // LSTM pointwise, parallel form (inf-safe, no clamp)
        const float sf = rcp_f(1.f + __expf(-gf));
        const float si = rcp_f(1.f + __expf(-gi));
        const float so = rcp_f(1.f + __expf(-go));
        const float tg = 1.f - 2.f * rcp_f(__expf(2.f * gg) + 1.f);
        const float cn = fmaf(sf, c, si * tg);
        const float th = 1.f - 2.f * rcp_f(__expf(2.f * cn) + 1.f);
        const float h  = so * th;
        c = cn;

        *outp = h;                   // store h(t) now; ack NOT drained at barrier
        outp += BATCH * HID;

        hbuf[(t + 1) & 1][cg] = h;   // publish new h for all waves
        STEP_BARRIER();              // lgkmcnt(0) + s_barrier (no vmcnt drain)
    }

    const size_t base = (size_t)T_STEPS * BATCH * HID;
    const float hfin = hbuf[T_STEPS & 1][cg];
    out[base + b * HID + cg] = hfin;
    out[base + BATCH * HID + b * HID + cg] = c;
}

extern "C" void kernel_launch(void* const* d_in, const int* in_sizes, int n_in,
                              void* d_out, int out_size, void* d_ws, size_t ws_size,
                              hipStream_t stream) {
    const float* x   = (const float*)d_in[0];   // (512,128,256)
    const float* hx  = (const float*)d_in[1];   // (128,256)
    const float* cx  = (const float*)d_in[2];   // (128,256)
    const float* Wp  = (const float*)d_in[3];   // (8,512)
    const float* qp  = (const float*)d_in[4];   // (8,)
    const float* Wg  = (const float*)d_in[5];   // (1024,8)
    const float* bg  = (const float*)d_in[6];   // (1024,)
    float* out = (float*)d_out;
    float* px  = (float*)d_ws;                  // 128*512*8 floats = 2 MB

    qlstm_projx<<<(T_STEPS * BATCH) / 4, 256, 0, stream>>>(x, Wp, qp, px);
    qlstm_seq<<<BATCH, 256, 0, stream>>>(hx, cx, Wp, Wg, bg, px, out);
}

// Round 14
// 277.403 us; speedup vs baseline: 1.2855x; 1.2855x over previous
//
#include <hip/hip_runtime.h>

#ifndef __has_builtin
#define __has_builtin(x) 0
#endif

#define T_STEPS 512
#define BATCH   128
#define DIN     256
#define HID     256
#define WPLD    (DIN + HID)   // 512

// Volatile asm loads: results are NOT rematerializable (cheap insurance).
#define ASM_LOAD4(dst, ptr) \
    asm volatile("global_load_dwordx4 %0, %1, off" : "=v"(dst) : "v"(ptr))
#define ASM_LOAD1(dst, ptr) \
    asm volatile("global_load_dword %0, %1, off" : "=v"(dst) : "v"(ptr))

// Barrier WITHOUT vmcnt drain (verified R11): waits only LDS ops; global
// h-stores stay in flight across it.
#define STEP_BARRIER() do {                                   \
    asm volatile("s_waitcnt lgkmcnt(0)" ::: "memory");        \
    __builtin_amdgcn_s_barrier();                             \
    __builtin_amdgcn_sched_barrier(0);                        \
} while (0)

// ---------------- cross-lane helpers (all verified in passing runs) ----------------
template<int CTRL>
__device__ __forceinline__ float dppmov(float x) {
    // 0xB1=quad xor1, 0x4E=quad xor2, 0x124=row_ror:4, 0x128=row_ror:8
    return __int_as_float(__builtin_amdgcn_update_dpp(0, __float_as_int(x), CTRL, 0xF, 0xF, true));
}
template<int PAT>
__device__ __forceinline__ float swz(float x) {
    return __int_as_float(__builtin_amdgcn_ds_swizzle(__float_as_int(x), PAT));
}
__device__ __forceinline__ float lane_xor16(float v, int l) {
#if __has_builtin(__builtin_amdgcn_permlane16_swap)
    auto r = __builtin_amdgcn_permlane16_swap(__float_as_uint(v), __float_as_uint(v), false, false);
    return __uint_as_float((l & 16) ? r[0] : r[1]);
#else
    return swz<0x401F>(v);
#endif
}
__device__ __forceinline__ float lane_xor32(float v, int l) {
#if __has_builtin(__builtin_amdgcn_permlane32_swap)
    auto r = __builtin_amdgcn_permlane32_swap(__float_as_uint(v), __float_as_uint(v), false, false);
    return __uint_as_float((l & 32) ? r[0] : r[1]);
#else
    return __shfl_xor(v, 32);
#endif
}
__device__ __forceinline__ float rcp_f(float x) {
#if __has_builtin(__builtin_amdgcn_rcpf)
    return __builtin_amdgcn_rcpf(x);
#else
    return 1.0f / x;
#endif
}

// ---------------------------------------------------------------------------
// Kernel 1: px[b][t][q] = sum_d x[t,b,d]*Wp[q,d] + qp[q]   (unchanged)
// ---------------------------------------------------------------------------
__global__ __launch_bounds__(256) void qlstm_projx(const float* __restrict__ x,
                                                   const float* __restrict__ Wp,
                                                   const float* __restrict__ qp,
                                                   float* __restrict__ px) {
    const int wave = threadIdx.x >> 6;
    const int lane = threadIdx.x & 63;
    const int row  = blockIdx.x * 4 + wave;       // row = t*BATCH + b

    const float4 xv = ((const float4*)(x + (size_t)row * DIN))[lane];
    float acc[8];
#pragma unroll
    for (int Q = 0; Q < 8; ++Q) {
        float4 w = ((const float4*)(Wp + Q * WPLD))[lane];
        acc[Q] = xv.x * w.x + xv.y * w.y + xv.z * w.z + xv.w * w.w;
    }
#pragma unroll
    for (int Q = 0; Q < 8; ++Q) {
        acc[Q] += dppmov<0xB1>(acc[Q]);
        acc[Q] += dppmov<0x4E>(acc[Q]);
        acc[Q] += swz<0x101F>(acc[Q]);
    }
    float p = acc[0];
#pragma unroll
    for (int j = 1; j < 8; ++j) p = ((lane & 7) == j) ? acc[j] : p;
    p += swz<0x201F>(p);
    p += swz<0x401F>(p);
    p += __shfl_xor(p, 32);
    if (lane < 8) {
        const int bb = row & (BATCH - 1);
        const int tt = row >> 7;
        px[(size_t)bb * (T_STEPS * 8) + tt * 8 + lane] = p + qp[lane];
    }
}

// ---------------------------------------------------------------------------
// Kernel 2: recurrence, two-phase step with wave-specialized reduction.
// Wave w computes ONLY q = 2w, 2w+1 (full-h dot + verified butterfly
// allreduce), publishes cos pair to LDS; bar1; all waves read the 8 cq
// (broadcast), prefix/gates/LSTM for their 64 columns; publish h; bar2.
// hbuf and cq are single-buffered (bar1 separates h-read from h-write;
// bar2 separates cq-read from next cq-write). Math bit-identical to R8.
// ---------------------------------------------------------------------------
__global__ __launch_bounds__(256, 1) void qlstm_seq(const float* __restrict__ hx,
                                                    const float* __restrict__ cx,
                                                    const float* __restrict__ Wp,
                                                    const float* __restrict__ Wg,
                                                    const float* __restrict__ bg,
                                                    const float* __restrict__ px,
                                                    float* __restrict__ out) {
    __shared__ float px_lds[(T_STEPS + 1) * 8];   // +8 pad for prefetch overrun
    __shared__ float hbuf[HID];                   // single-buffered h
    __shared__ float cq_lds[8];                   // single-buffered cos values

    const int tid = threadIdx.x;
    const int w   = tid >> 6;     // wave id 0..3 -> owns q=2w,2w+1
    const int l   = tid & 63;     // lane
    const int b   = blockIdx.x;
    const int cg  = tid;          // this thread's gate/LSTM column
    const bool lane0 = (l == 0);

    // ---- weight loads (asm: non-rematerializable) ----
    float4 wph0, wph1;            // Wp[2w][256+4l..], Wp[2w+1][256+4l..]
    {
        const float* a0 = Wp + (2 * w) * WPLD + DIN + 4 * l;
        const float* a1 = Wp + (2 * w + 1) * WPLD + DIN + 4 * l;
        ASM_LOAD4(wph0, a0);
        ASM_LOAD4(wph1, a1);
    }
    float4 WG0[4], WG1[4];        // Wg row (G*256+cg), floats 0..7
#pragma unroll
    for (int G = 0; G < 4; ++G) {
        const float* r = Wg + (size_t)(G * HID + cg) * 8;
        ASM_LOAD4(WG0[G], r);
        ASM_LOAD4(WG1[G], r + 4);
    }
    float bgc[4];                 // bg[G*256+cg]
#pragma unroll
    for (int G = 0; G < 4; ++G) {
        const float* a = bg + G * HID + cg;
        ASM_LOAD1(bgc[G], a);
    }

    // preload all px for this b (4096 floats = 1024 float4, 4 per thread)
    {
        const float4* pg = (const float4*)(px + (size_t)b * (T_STEPS * 8));
        float4* pl = (float4*)px_lds;
#pragma unroll
        for (int j = 0; j < 4; ++j) pl[j * 256 + tid] = pg[j * 256 + tid];
    }

    float c = cx[b * HID + cg];
    hbuf[tid] = hx[b * HID + tid];

    asm volatile("s_waitcnt vmcnt(0)" ::: "memory");
    __builtin_amdgcn_sched_barrier(0);
    __syncthreads();   // hbuf + px_lds ready (prologue only)

    // prefetch this wave's px pair for t=0
    float2 pxp = *(const float2*)&px_lds[2 * w];

    float* outp = out + (size_t)b * HID + cg;
    float h = 0.f;

    for (int t = 0; t < T_STEPS; ++t) {
        // ---- phase 1: this wave's two q-dots over the full h ----
        const float4 h4 = *(const float4*)&hbuf[4 * l];

        float v0 = lane0 ? pxp.x : 0.f;
        v0 = fmaf(h4.x, wph0.x, v0);
        v0 = fmaf(h4.y, wph0.y, v0);
        v0 = fmaf(h4.z, wph0.z, v0);
        v0 = fmaf(h4.w, wph0.w, v0);
        float v1 = lane0 ? pxp.y : 0.f;
        v1 = fmaf(h4.x, wph1.x, v1);
        v1 = fmaf(h4.y, wph1.y, v1);
        v1 = fmaf(h4.z, wph1.z, v1);
        v1 = fmaf(h4.w, wph1.w, v1);

        // verified butterfly allreduce (two interleaved chains)
        v0 += dppmov<0xB1>(v0);   v1 += dppmov<0xB1>(v1);    // xor1
        v0 += dppmov<0x4E>(v0);   v1 += dppmov<0x4E>(v1);    // xor2
        v0 += dppmov<0x124>(v0);  v1 += dppmov<0x124>(v1);   // ror4
        v0 += dppmov<0x128>(v0);  v1 += dppmov<0x128>(v1);   // ror8
        v0 += lane_xor16(v0, l);  v1 += lane_xor16(v1, l);
        v0 += lane_xor32(v0, l);  v1 += lane_xor32(v1, l);

        const float cq0 = __cosf(v0);
        const float cq1 = __cosf(v1);
        if (lane0) {
            *(float2*)&cq_lds[2 * w] = make_float2(cq0, cq1);
        }
        STEP_BARRIER();   // bar1: cq visible; also separates h-read from h-write

        // ---- phase 2: gates/LSTM for this thread's column ----
        const float4 cqa = *(const float4*)&cq_lds[0];
        const float4 cqb = *(const float4*)&cq_lds[4];

        // prefetch px pair for t+1 (independent of cq)
        pxp = *(const float2*)&px_lds[(t + 1) * 8 + 2 * w];

        const float C0 = cqa.x, C1 = cqa.y, C2 = cqa.z, C3 = cqa.w;
        const float C4 = cqb.x, C5 = cqb.y, C6 = cqb.z, C7 = cqb.w;

        // prefix products: qo[0]=C1..C7, qo[k>=1]=C0..Ck
        const float d01 = C0 * C1, d23 = C2 * C3, d45 = C4 * C5, d67 = C6 * C7;
        float qo[8];
        qo[1] = d01;
        qo[2] = d01 * C2;
        qo[3] = d01 * d23;
        qo[4] = qo[3] * C4;
        qo[5] = qo[3] * d45;
        qo[6] = qo[5] * C6;
        qo[7] = qo[5] * d67;
        qo[0] = (C1 * d23) * (d45 * d67);

        // gates for this thread's single column (tree-structured, as R8)
        float gf, gi, gg, go;
        {
            float a0, a1;
            a0 = fmaf(WG0[0].x, qo[0], bgc[0]);  a0 = fmaf(WG0[0].y, qo[1], a0);
            a0 = fmaf(WG0[0].z, qo[2], a0);      a0 = fmaf(WG0[0].w, qo[3], a0);
            a1 = WG1[0].x * qo[4];               a1 = fmaf(WG1[0].y, qo[5], a1);
            a1 = fmaf(WG1[0].z, qo[6], a1);      a1 = fmaf(WG1[0].w, qo[7], a1);
            gf = a0 + a1;
            a0 = fmaf(WG0[1].x, qo[0], bgc[1]);  a0 = fmaf(WG0[1].y, qo[1], a0);
            a0 = fmaf(WG0[1].z, qo[2], a0);      a0 = fmaf(WG0[1].w, qo[3], a0);
            a1 = WG1[1].x * qo[4];               a1 = fmaf(WG1[1].y, qo[5], a1);
            a1 = fmaf(WG1[1].z, qo[6], a1);      a1 = fmaf(WG1[1].w, qo[7], a1);
            gi = a0 + a1;
            a0 = fmaf(WG0[2].x, qo[0], bgc[2]);  a0 = fmaf(WG0[2].y, qo[1], a0);
            a0 = fmaf(WG0[2].z, qo[2], a0);      a0 = fmaf(WG0[2].w, qo[3], a0);
            a1 = WG1[2].x * qo[4];               a1 = fmaf(WG1[2].y, qo[5], a1);
            a1 = fmaf(WG1[2].z, qo[6], a1);      a1 = fmaf(WG1[2].w, qo[7], a1);
            gg = a0 + a1;
            a0 = fmaf(WG0[3].x, qo[0], bgc[3]);  a0 = fmaf(WG0[3].y, qo[1], a0);
            a0 = fmaf(WG0[3].z, qo[2], a0);      a0 = fmaf(WG0[3].w, qo[3], a0);
            a1 = WG1[3].x * qo[4];               a1 = fmaf(WG1[3].y, qo[5], a1);
            a1 = fmaf(WG1[3].z, qo[6], a1);      a1 = fmaf(WG1[3].w, qo[7], a1);
            go = a0 + a1;
        }

        // LSTM pointwise, parallel form (inf-safe, no clamp) — as R8
        const float sf = rcp_f(1.f + __expf(-gf));
        const float si = rcp_f(1.f + __expf(-gi));
        const float so = rcp_f(1.f + __expf(-go));
        const float tg = 1.f - 2.f * rcp_f(__expf(2.f * gg) + 1.f);
        const float cn = fmaf(sf, c, si * tg);
        const float th = 1.f - 2.f * rcp_f(__expf(2.f * cn) + 1.f);
        h = so * th;
        c = cn;

        *outp = h;                   // global store; not drained at barriers
        outp += BATCH * HID;

        hbuf[cg] = h;                // publish new h
        STEP_BARRIER();              // bar2: h visible; separates cq read/write
    }

    const size_t base = (size_t)T_STEPS * BATCH * HID;
    out[base + b * HID + cg] = h;
    out[base + BATCH * HID + b * HID + cg] = c;
}

extern "C" void kernel_launch(void* const* d_in, const int* in_sizes, int n_in,
                              void* d_out, int out_size, void* d_ws, size_t ws_size,
                              hipStream_t stream) {
    const float* x   = (const float*)d_in[0];   // (512,128,256)
    const float* hx  = (const float*)d_in[1];   // (128,256)
    const float* cx  = (const float*)d_in[2];   // (128,256)
    const float* Wp  = (const float*)d_in[3];   // (8,512)
    const float* qp  = (const float*)d_in[4];   // (8,)
    const float* Wg  = (const float*)d_in[5];   // (1024,8)
    const float* bg  = (const float*)d_in[6];   // (1024,)
    float* out = (float*)d_out;
    float* px  = (float*)d_ws;                  // 128*512*8 floats = 2 MB

    qlstm_projx<<<(T_STEPS * BATCH) / 4, 256, 0, stream>>>(x, Wp, qp, px);
    qlstm_seq<<<BATCH, 256, 0, stream>>>(hx, cx, Wp, Wg, bg, px, out);
}